// Round 2
// baseline (1967.717 us; speedup 1.0000x reference)
//
#include <hip/hip_runtime.h>

typedef unsigned int u32;

// ---------- preprocessing ----------

// Detect int64 vs int32 edge_index: for int64 (values < 2^31, nonneg) every odd
// 32-bit word is the zero high-half; for int32 data odd words are random indices.
__global__ void k_detect(const u32* __restrict__ ei, int n, u32* __restrict__ flag){
  int t = blockIdx.x * blockDim.x + threadIdx.x;
  u32 v = 0;
  if (t < n) v = ei[2 * t + 1];
  unsigned long long b = __ballot(v != 0u);
  if ((threadIdx.x & 63) == 0 && b) atomicOr(flag, 1u);
}

__global__ void k_conv(const int* __restrict__ ei, int* __restrict__ src, int* __restrict__ dst,
                       int E, const u32* __restrict__ flag){
  int e = blockIdx.x * blockDim.x + threadIdx.x;
  if (e >= E) return;
  bool is64 = (*flag == 0u);
  if (is64){ src[e] = ei[2 * e]; dst[e] = ei[2 * (E + e)]; }
  else     { src[e] = ei[e];     dst[e] = ei[E + e]; }
}

__global__ void k_hist(const int* __restrict__ dst, int* __restrict__ deg, int E){
  int e = blockIdx.x * blockDim.x + threadIdx.x;
  if (e < E) atomicAdd(&deg[dst[e]], 1);
}

// single-block shfl-based scan (exclusive), seg[n] = total
__global__ __launch_bounds__(1024) void k_scan(const int* __restrict__ deg, int* __restrict__ seg, int n){
  __shared__ int wsum[16];
  __shared__ int carry_s;
  int t = threadIdx.x, lane = t & 63, w = t >> 6;
  if (t == 0) carry_s = 0;
  __syncthreads();
  for (int base = 0; base < n; base += 1024){
    int i = base + t;
    int v = (i < n) ? deg[i] : 0;
    int x = v;
    #pragma unroll
    for (int off = 1; off < 64; off <<= 1){
      int y = __shfl_up(x, off);
      if (lane >= off) x += y;
    }
    if (lane == 63) wsum[w] = x;
    __syncthreads();
    if (w == 0 && lane < 16){
      int sv = wsum[lane];
      #pragma unroll
      for (int off = 1; off < 16; off <<= 1){
        int y = __shfl_up(sv, off);
        if (lane >= off) sv += y;
      }
      wsum[lane] = sv;
    }
    __syncthreads();
    int woff = (w > 0) ? wsum[w - 1] : 0;
    int carry = carry_s;
    int incl = carry + woff + x;
    if (i < n) seg[i] = incl - v;          // exclusive
    __syncthreads();
    if (t == 1023) carry_s = incl;         // tile total + carry
    __syncthreads();
  }
  if (threadIdx.x == 0) seg[n] = carry_s;
}

__global__ void k_scatter(const int* __restrict__ src, const int* __restrict__ dst,
                          const int* __restrict__ seg, int* __restrict__ cur,
                          int* __restrict__ ssrc, int* __restrict__ seid, int E){
  int e = blockIdx.x * blockDim.x + threadIdx.x;
  if (e >= E) return;
  int d = dst[e];
  int pos = seg[d] + atomicAdd(&cur[d], 1);
  ssrc[pos] = src[e];
  seid[pos] = e;
}

// ---------- node transform: xl = A@Wl, xr = A@Wr (all f32; W [128,128]) ----------
__global__ __launch_bounds__(256) void k_gemm(const float* __restrict__ A,
    const float* __restrict__ Wl, const float* __restrict__ Wr,
    float* __restrict__ xl, float* __restrict__ xr, int nrows)
{
  __shared__ float sA[32][128];   // 16 KB
  __shared__ float sW[32][256];   // 32 KB (stage of 32 K-rows, Wl|Wr concat)
  int t  = threadIdx.x;
  int rb = blockIdx.x * 32;

  #pragma unroll
  for (int i = 0; i < 4; i++){
    int f = t * 16 + i * 4;        // 16 floats per thread, 4 per float4
    int r = f >> 7, c = f & 127;
    int gr = rb + r;
    float4 v = make_float4(0.f, 0.f, 0.f, 0.f);
    if (gr < nrows) v = *(const float4*)(A + (size_t)gr * 128 + c);
    *(float4*)&sA[r][c] = v;
  }

  int r0 = (t >> 5) * 4;        // 4 rows
  int c0 = (t & 31) * 8;        // 8 cols
  float acc[4][8];
  #pragma unroll
  for (int r = 0; r < 4; r++)
    #pragma unroll
    for (int j = 0; j < 8; j++) acc[r][j] = 0.f;

  for (int ko = 0; ko < 128; ko += 32){
    __syncthreads();
    #pragma unroll
    for (int i = 0; i < 8; i++){
      int q = i * 256 + t;          // float4 index in [0,2048)
      int kl = q >> 6, c = (q & 63) * 4;
      float4 v;
      if (c < 128) v = *(const float4*)(Wl + (size_t)(ko + kl) * 128 + c);
      else         v = *(const float4*)(Wr + (size_t)(ko + kl) * 128 + (c - 128));
      *(float4*)&sW[kl][c] = v;
    }
    __syncthreads();
    #pragma unroll 4
    for (int kl = 0; kl < 32; kl++){
      int k = ko + kl;
      float a0 = sA[r0][k], a1 = sA[r0 + 1][k], a2 = sA[r0 + 2][k], a3 = sA[r0 + 3][k];
      float4 wA = *(float4*)&sW[kl][c0];
      float4 wB = *(float4*)&sW[kl][c0 + 4];
      float wv[8] = { wA.x, wA.y, wA.z, wA.w, wB.x, wB.y, wB.z, wB.w };
      #pragma unroll
      for (int j = 0; j < 8; j++){
        acc[0][j] = fmaf(a0, wv[j], acc[0][j]);
        acc[1][j] = fmaf(a1, wv[j], acc[1][j]);
        acc[2][j] = fmaf(a2, wv[j], acc[2][j]);
        acc[3][j] = fmaf(a3, wv[j], acc[3][j]);
      }
    }
  }

  float* outp = (c0 < 128) ? xl : xr;
  int cc = c0 & 127;
  #pragma unroll
  for (int r = 0; r < 4; r++){
    int gr = rb + r0 + r;
    if (gr < nrows){
      *(float4*)(outp + (size_t)gr * 128 + cc)     = make_float4(acc[r][0], acc[r][1], acc[r][2], acc[r][3]);
      *(float4*)(outp + (size_t)gr * 128 + cc + 4) = make_float4(acc[r][4], acc[r][5], acc[r][6], acc[r][7]);
    }
  }
}

// ---------- fused per-node attention (one wave per dst node, online softmax) ----------
// lane owns channels (2*lane, 2*lane+1); head = lane>>5; logit reduced per 32-lane half.
template<int RELU>
__global__ __launch_bounds__(256) void k_seg(
    const int* __restrict__ seg, const int* __restrict__ ssrc, const int* __restrict__ seid,
    const float* __restrict__ xl, const float* __restrict__ xr,
    const float* __restrict__ eattr, const float* __restrict__ We,
    const float* __restrict__ att, const float* __restrict__ bias,
    float* __restrict__ out, int N)
{
  int wid  = blockIdx.x * 4 + (threadIdx.x >> 6);
  int lane = threadIdx.x & 63;
  if (wid >= N) return;
  int c0 = lane * 2;

  float w0[32], w1[32];                 // We columns c0, c0+1
  #pragma unroll
  for (int k = 0; k < 32; k++){
    float2 w = *(const float2*)(We + k * 128 + c0);
    w0[k] = w.x; w1[k] = w.y;
  }
  float2 av  = *(const float2*)(att + c0);
  float2 xrv = *(const float2*)(xr + (size_t)wid * 128 + c0);

  float m = -3.0e38f, s = 0.f, o0 = 0.f, o1 = 0.f;
  int p = seg[wid], pend = seg[wid + 1];
  for (; p < pend; ++p){
    int sn  = ssrc[p];
    int eid = seid[p];
    float2 xj = *(const float2*)(xl + (size_t)sn * 128 + c0);
    const float4* ep = (const float4*)(eattr + (size_t)eid * 32);
    float ea0 = 0.f, ea1 = 0.f;
    #pragma unroll
    for (int i = 0; i < 8; i++){
      float4 e4 = ep[i];
      ea0 = fmaf(e4.x, w0[4*i], fmaf(e4.y, w0[4*i+1], fmaf(e4.z, w0[4*i+2], fmaf(e4.w, w0[4*i+3], ea0))));
      ea1 = fmaf(e4.x, w1[4*i], fmaf(e4.y, w1[4*i+1], fmaf(e4.z, w1[4*i+2], fmaf(e4.w, w1[4*i+3], ea1))));
    }
    float v0 = xj.x + xrv.x + ea0; v0 = fmaxf(v0, 0.2f * v0);
    float v1 = xj.y + xrv.y + ea1; v1 = fmaxf(v1, 0.2f * v1);
    float zp = fmaf(v0, av.x, v1 * av.y);
    zp += __shfl_xor(zp, 1);
    zp += __shfl_xor(zp, 2);
    zp += __shfl_xor(zp, 4);
    zp += __shfl_xor(zp, 8);
    zp += __shfl_xor(zp, 16);          // per-half-wave sum = logit for this head
    float nm = fmaxf(m, zp);
    float sc = __expf(m - nm);
    float pr = __expf(zp - nm);
    s  = fmaf(s,  sc, pr);
    o0 = fmaf(o0, sc, pr * xj.x);
    o1 = fmaf(o1, sc, pr * xj.y);
    m = nm;
  }
  float inv = 1.0f / (s + 1e-16f);
  float2 bv = *(const float2*)(bias + c0);
  float r0 = fmaf(o0, inv, bv.x);
  float r1 = fmaf(o1, inv, bv.y);
  if (RELU){ r0 = fmaxf(r0, 0.f); r1 = fmaxf(r1, 0.f); }
  *(float2*)(out + (size_t)wid * 128 + c0) = make_float2(r0, r1);
}

// ---------- launch ----------
extern "C" void kernel_launch(void* const* d_in, const int* in_sizes, int n_in,
                              void* d_out, int out_size, void* d_ws, size_t ws_size,
                              hipStream_t stream)
{
  const float* x     = (const float*)d_in[0];
  const int*   ei    = (const int*)  d_in[1];
  const float* eattr = (const float*)d_in[2];
  const float* Wp[3][5];
  for (int l = 0; l < 3; l++)
    for (int j = 0; j < 5; j++)
      Wp[l][j] = (const float*)d_in[3 + l * 5 + j];

  int N = in_sizes[0] / 128;
  int E = in_sizes[2] / 32;

  char* w = (char*)d_ws;
  auto alloc = [&](size_t bytes) -> char* {
    char* p = w; w += (bytes + 255) & ~(size_t)255; return p;
  };
  float* xl  = (float*)alloc((size_t)N * 128 * 4);
  float* xr  = (float*)alloc((size_t)N * 128 * 4);   // also inter-layer h buffer
  int* srcA  = (int*)alloc((size_t)E * 4);
  int* dstA  = (int*)alloc((size_t)E * 4);
  int* ssrc  = (int*)alloc((size_t)E * 4);
  int* seid  = (int*)alloc((size_t)E * 4);
  int* deg   = (int*)alloc((size_t)N * 4);
  int* cur   = (int*)alloc((size_t)N * 4);
  int* seg   = (int*)alloc((size_t)(N + 1) * 4);
  u32* flag  = (u32*)alloc(256);

  hipMemsetAsync(deg,  0, (size_t)N * 4, stream);
  hipMemsetAsync(cur,  0, (size_t)N * 4, stream);
  hipMemsetAsync(flag, 0, 4, stream);

  int ndet = (E < 16384) ? E : 16384;
  k_detect<<<(ndet + 255) / 256, 256, 0, stream>>>((const u32*)ei, ndet, flag);
  int gE = (E + 255) / 256;
  k_conv<<<gE, 256, 0, stream>>>(ei, srcA, dstA, E, flag);
  k_hist<<<gE, 256, 0, stream>>>(dstA, deg, E);
  k_scan<<<1, 1024, 0, stream>>>(deg, seg, N);
  k_scatter<<<gE, 256, 0, stream>>>(srcA, dstA, seg, cur, ssrc, seid, E);

  int gG = (N + 31) / 32;
  int gS = (N + 3) / 4;
  // layer 0: A = x
  k_gemm<<<gG, 256, 0, stream>>>(x,  Wp[0][0], Wp[0][1], xl, xr, N);
  k_seg<1><<<gS, 256, 0, stream>>>(seg, ssrc, seid, xl, xr, eattr, Wp[0][2], Wp[0][3], Wp[0][4], xr, N);
  // layer 1: A = h (in xr)
  k_gemm<<<gG, 256, 0, stream>>>(xr, Wp[1][0], Wp[1][1], xl, xr, N);
  k_seg<1><<<gS, 256, 0, stream>>>(seg, ssrc, seid, xl, xr, eattr, Wp[1][2], Wp[1][3], Wp[1][4], xr, N);
  // layer 2: A = h (in xr) -> d_out, no relu
  k_gemm<<<gG, 256, 0, stream>>>(xr, Wp[2][0], Wp[2][1], xl, xr, N);
  k_seg<0><<<gS, 256, 0, stream>>>(seg, ssrc, seid, xl, xr, eattr, Wp[2][2], Wp[2][3], Wp[2][4], (float*)d_out, N);
}